// Round 2
// baseline (306.333 us; speedup 1.0000x reference)
//
#include <hip/hip_runtime.h>
#include <math.h>

#define BROWS 65536
#define DIM 512
#define NHEAD 64
#define NCOL 128   // NHEAD*2

#define PRED_SZ   (BROWS * (size_t)NCOL)          // 8388608 floats
#define ARG_BASE  PRED_SZ                          // argmax region start (floats)
#define LOSS_IDX  (PRED_SZ + (size_t)BROWS * NHEAD)  // 12582912
// Borrowed inside argmax region:
//   rows    0..1023  -> Bmat[512][128]  (65536 floats)
//   rows 1056..1087  -> per-block loss partials (2048 floats)
// GEMM skips argmax stores for rows < 1088; fixup kernel rewrites them.
#define BMAT_OFF   ARG_BASE
#define PART_OFF   (ARG_BASE + 1056 * (size_t)NHEAD)
#define FIX_ROWS   1088

__global__ __launch_bounds__(64) void spectral_kernel(
    const float* __restrict__ W, const float* __restrict__ u,
    float* __restrict__ Bmat)
{
    int n = blockIdx.x;       // head
    int lane = threadIdx.x;   // 0..63

    const float* W0 = W + (size_t)n * 2 * DIM;
    const float* W1 = W0 + DIM;
    float u0 = u[n * 2 + 0], u1v = u[n * 2 + 1];

    float w0[8], w1[8], vr[8];
    float ss = 0.f;
#pragma unroll
    for (int i = 0; i < 8; ++i) {
        int d = lane + 64 * i;
        w0[i] = W0[d]; w1[i] = W1[d];
        vr[i] = fmaf(w0[i], u0, w1[i] * u1v);
        ss = fmaf(vr[i], vr[i], ss);
    }
#pragma unroll
    for (int m = 32; m >= 1; m >>= 1) ss += __shfl_xor(ss, m, 64);
    float inv_n = 1.f / fmaxf(sqrtf(ss), 1e-12f);

    float s0 = 0.f, s1 = 0.f;
#pragma unroll
    for (int i = 0; i < 8; ++i) {
        float v = vr[i] * inv_n;
        s0 = fmaf(w0[i], v, s0);
        s1 = fmaf(w1[i], v, s1);
    }
#pragma unroll
    for (int m = 32; m >= 1; m >>= 1) {
        s0 += __shfl_xor(s0, m, 64);
        s1 += __shfl_xor(s1, m, 64);
    }
    float nu = sqrtf(fmaf(s0, s0, s1 * s1));
    float inv_nu = 1.f / fmaxf(nu, 1e-12f);
    float uu0 = s0 * inv_nu, uu1 = s1 * inv_nu;
    float sigma = fmaf(uu0, s0, uu1 * s1);
    float inv_sigma = 1.f / sigma;

#pragma unroll
    for (int i = 0; i < 8; ++i) {
        int d = lane + 64 * i;
        Bmat[(size_t)d * NCOL + 2 * n + 0] = w0[i] * inv_sigma;
        Bmat[(size_t)d * NCOL + 2 * n + 1] = w1[i] * inv_sigma;
    }
}

// 256 threads, 32 rows x 128 cols per block; thread tile 4 rows x 4 cols.
__global__ __launch_bounds__(256) void gemm_fused(
    const float* __restrict__ A, const int* __restrict__ target,
    const float* __restrict__ Bmat, const float* __restrict__ bias,
    float* __restrict__ pred, float* __restrict__ outArg,
    float* __restrict__ partials)
{
    __shared__ float As[32][36];    // [k][row], padded
    __shared__ float Bs[32][128];   // [k][col]
    __shared__ float wsum[4];

    int tid = threadIdx.x;
    int rowBase = blockIdx.x * 32;
    int rg = tid >> 5;       // 0..7  (row group, 4 rows each)
    int cg = tid & 31;       // 0..31 (col group, 4 cols each)
    int r0 = rg * 4;
    int c0 = cg * 4;

    float acc[4][4] = {{0.f}};

    for (int kc = 0; kc < DIM; kc += 32) {
        {
            int lr = tid >> 3;          // 0..31 row
            int lk = (tid & 7) * 4;     // 0,4,..,28
            const float4 a4 = *(const float4*)(A + (size_t)(rowBase + lr) * DIM + kc + lk);
            As[lk + 0][lr] = a4.x;
            As[lk + 1][lr] = a4.y;
            As[lk + 2][lr] = a4.z;
            As[lk + 3][lr] = a4.w;
        }
        {
            int lk = tid >> 5;          // 0..7
            int lc = (tid & 31) * 4;
#pragma unroll
            for (int i = 0; i < 4; ++i) {
                *(float4*)(&Bs[lk + 8 * i][lc]) =
                    *(const float4*)(Bmat + (size_t)(kc + lk + 8 * i) * NCOL + lc);
            }
        }
        __syncthreads();
#pragma unroll
        for (int k = 0; k < 32; ++k) {
            float4 a4 = *(const float4*)(&As[k][r0]);   // broadcast within half-wave
            float4 b4 = *(const float4*)(&Bs[k][c0]);
            acc[0][0] = fmaf(a4.x, b4.x, acc[0][0]);
            acc[0][1] = fmaf(a4.x, b4.y, acc[0][1]);
            acc[0][2] = fmaf(a4.x, b4.z, acc[0][2]);
            acc[0][3] = fmaf(a4.x, b4.w, acc[0][3]);
            acc[1][0] = fmaf(a4.y, b4.x, acc[1][0]);
            acc[1][1] = fmaf(a4.y, b4.y, acc[1][1]);
            acc[1][2] = fmaf(a4.y, b4.z, acc[1][2]);
            acc[1][3] = fmaf(a4.y, b4.w, acc[1][3]);
            acc[2][0] = fmaf(a4.z, b4.x, acc[2][0]);
            acc[2][1] = fmaf(a4.z, b4.y, acc[2][1]);
            acc[2][2] = fmaf(a4.z, b4.z, acc[2][2]);
            acc[2][3] = fmaf(a4.z, b4.w, acc[2][3]);
            acc[3][0] = fmaf(a4.w, b4.x, acc[3][0]);
            acc[3][1] = fmaf(a4.w, b4.y, acc[3][1]);
            acc[3][2] = fmaf(a4.w, b4.z, acc[3][2]);
            acc[3][3] = fmaf(a4.w, b4.w, acc[3][3]);
        }
        __syncthreads();
    }

    // ---- epilogue ----
    float b0 = bias[c0 + 0], b1 = bias[c0 + 1], b2 = bias[c0 + 2], b3 = bias[c0 + 3];
    int h0 = c0 >> 1;   // heads h0 (cols c0,c0+1) and h0+1 (cols c0+2,c0+3)
    bool doArg = (rowBase >= FIX_ROWS);   // rows < 1088 fixed up later

    float lp = 0.f;
#pragma unroll
    for (int r = 0; r < 4; ++r) {
        int row = rowBase + r0 + r;
        float p0 = acc[r][0] + b0;
        float p1 = acc[r][1] + b1;
        float p2 = acc[r][2] + b2;
        float p3 = acc[r][3] + b3;

        *(float4*)(pred + (size_t)row * NCOL + c0) = make_float4(p0, p1, p2, p3);

        if (doArg) {
            outArg[(size_t)row * NHEAD + h0]     = (p1 > p0) ? 1.f : 0.f;
            outArg[(size_t)row * NHEAD + h0 + 1] = (p3 > p2) ? 1.f : 0.f;
        }

        // LSE over the 64 heads (axis=1); masks <32 stay within the half-wave
        float M0 = fmaxf(p0, p2), M1 = fmaxf(p1, p3);
#pragma unroll
        for (int m = 16; m >= 1; m >>= 1) {
            M0 = fmaxf(M0, __shfl_xor(M0, m, 64));
            M1 = fmaxf(M1, __shfl_xor(M1, m, 64));
        }
        float s0 = expf(p0 - M0) + expf(p2 - M0);
        float s1 = expf(p1 - M1) + expf(p3 - M1);
#pragma unroll
        for (int m = 16; m >= 1; m >>= 1) {
            s0 += __shfl_xor(s0, m, 64);
            s1 += __shfl_xor(s1, m, 64);
        }
        float L0 = M0 + logf(s0);
        float L1 = M1 + logf(s1);

        int t0 = target[(size_t)row * NHEAD + h0];
        int t1 = target[(size_t)row * NHEAD + h0 + 1];
        lp += t0 ? (L1 - p1) : (L0 - p0);
        lp += t1 ? (L1 - p3) : (L0 - p2);
    }

    // deterministic block partial: wave butterfly, then fixed-order combine
#pragma unroll
    for (int m = 32; m >= 1; m >>= 1) lp += __shfl_xor(lp, m, 64);
    if ((tid & 63) == 0) wsum[tid >> 6] = lp;
    __syncthreads();
    if (tid == 0)
        partials[blockIdx.x] = (wsum[0] + wsum[1]) + (wsum[2] + wsum[3]);
}

// block 0: deterministic loss reduction + argmax rows 1056..1087 (partials region)
// blocks 1..66: argmax fixup rows 0..1055 (Bmat + untouched window)
__global__ __launch_bounds__(256) void fixup_kernel(
    const float* __restrict__ pred, const float* __restrict__ partials,
    float* __restrict__ outArg, float* __restrict__ lossOut)
{
    int tid = threadIdx.x;
    if (blockIdx.x == 0) {
        __shared__ double red[256];
        double s = 0.0;
#pragma unroll
        for (int i = 0; i < 8; ++i) s += (double)partials[tid * 8 + i];
        red[tid] = s;
        __syncthreads();
        for (int m = 128; m >= 1; m >>= 1) {
            if (tid < m) red[tid] += red[tid + m];
            __syncthreads();
        }
        if (tid == 0) lossOut[0] = (float)(red[0] / 131072.0);
        __syncthreads();
        // now safe to overwrite the partials region rows (1056..1087)
        int row = 1056 + (tid >> 3);
        int hb = (tid & 7) * 8;
        const float* pr = pred + (size_t)row * NCOL;
        float* ar = outArg + (size_t)row * NHEAD;
#pragma unroll
        for (int h = 0; h < 8; ++h) {
            float a = pr[2 * (hb + h)], b = pr[2 * (hb + h) + 1];
            ar[hb + h] = (b > a) ? 1.f : 0.f;
        }
    } else {
        int row = (blockIdx.x - 1) * 16 + (tid >> 4);
        int hb = (tid & 15) * 4;
        const float* pr = pred + (size_t)row * NCOL;
        float* ar = outArg + (size_t)row * NHEAD;
#pragma unroll
        for (int h = 0; h < 4; ++h) {
            float a = pr[2 * (hb + h)], b = pr[2 * (hb + h) + 1];
            ar[hb + h] = (b > a) ? 1.f : 0.f;
        }
    }
}

extern "C" void kernel_launch(void* const* d_in, const int* in_sizes, int n_in,
                              void* d_out, int out_size, void* d_ws, size_t ws_size,
                              hipStream_t stream) {
    const float* feature = (const float*)d_in[0];   // [65536,512]
    const int*   target  = (const int*)d_in[1];     // [65536,64]
    const float* W       = (const float*)d_in[2];   // [64,2,512]
    const float* bias    = (const float*)d_in[3];   // [64,2]
    const float* u       = (const float*)d_in[4];   // [64,2]

    float* out     = (float*)d_out;
    float* pred    = out;
    float* outArg  = out + ARG_BASE;
    float* lossOut = out + LOSS_IDX;
    float* Bmat    = out + BMAT_OFF;   // borrowed: argmax rows 0..1023
    float* partial = out + PART_OFF;   // borrowed: argmax rows 1056..1087

    spectral_kernel<<<NHEAD, 64, 0, stream>>>(W, u, Bmat);
    gemm_fused<<<BROWS / 32, 256, 0, stream>>>(feature, target, Bmat, bias,
                                               pred, outArg, partial);
    fixup_kernel<<<67, 256, 0, stream>>>(pred, partial, outArg, lossOut);
}

// Round 3
// 285.631 us; speedup vs baseline: 1.0725x; 1.0725x over previous
//
#include <hip/hip_runtime.h>
#include <math.h>

typedef __bf16 bf16x8 __attribute__((ext_vector_type(8)));
typedef float  f32x4  __attribute__((ext_vector_type(4)));

#define BROWS 65536
#define DIM   512
#define NHEAD 64
#define NCOL  128

#define PRED_SZ  ((size_t)BROWS * NCOL)            // 8388608 floats
#define ARG_BASE PRED_SZ
#define LOSS_IDX (PRED_SZ + (size_t)BROWS * NHEAD)
// Borrowed inside argmax region (rewritten by fixup):
//   rows    0..1023 : B_hiT[128][512] bf16 (32768 f) + B_loT (32768 f)
//   rows 1056..1063 : 512 per-block loss partials
#define BH_OFF   ARG_BASE
#define BL_OFF   (ARG_BASE + 32768)
#define PART_OFF (ARG_BASE + 1056 * (size_t)NHEAD)
#define FIX_ROWS 1088

__global__ __launch_bounds__(64) void spectral_kernel(
    const float* __restrict__ W, const float* __restrict__ u,
    __bf16* __restrict__ Bh, __bf16* __restrict__ Bl)
{
    int n = blockIdx.x;       // head
    int lane = threadIdx.x;   // 0..63

    const float* W0 = W + (size_t)n * 2 * DIM;
    const float* W1 = W0 + DIM;
    float u0 = u[n * 2 + 0], u1v = u[n * 2 + 1];

    float w0[8], w1[8], vr[8];
    float ss = 0.f;
#pragma unroll
    for (int i = 0; i < 8; ++i) {
        int d = lane + 64 * i;
        w0[i] = W0[d]; w1[i] = W1[d];
        vr[i] = fmaf(w0[i], u0, w1[i] * u1v);
        ss = fmaf(vr[i], vr[i], ss);
    }
#pragma unroll
    for (int m = 32; m >= 1; m >>= 1) ss += __shfl_xor(ss, m, 64);
    float inv_n = 1.f / fmaxf(sqrtf(ss), 1e-12f);

    float s0 = 0.f, s1 = 0.f;
#pragma unroll
    for (int i = 0; i < 8; ++i) {
        float v = vr[i] * inv_n;
        s0 = fmaf(w0[i], v, s0);
        s1 = fmaf(w1[i], v, s1);
    }
#pragma unroll
    for (int m = 32; m >= 1; m >>= 1) {
        s0 += __shfl_xor(s0, m, 64);
        s1 += __shfl_xor(s1, m, 64);
    }
    float nu = sqrtf(fmaf(s0, s0, s1 * s1));
    float inv_nu = 1.f / fmaxf(nu, 1e-12f);
    float uu0 = s0 * inv_nu, uu1 = s1 * inv_nu;
    float sigma = fmaf(uu0, s0, uu1 * s1);
    float inv_sigma = 1.f / sigma;

#pragma unroll
    for (int i = 0; i < 8; ++i) {
        int d = lane + 64 * i;
        float x0 = w0[i] * inv_sigma;
        float x1 = w1[i] * inv_sigma;
        __bf16 h0 = (__bf16)x0;
        __bf16 h1 = (__bf16)x1;
        Bh[(size_t)(2 * n + 0) * DIM + d] = h0;
        Bh[(size_t)(2 * n + 1) * DIM + d] = h1;
        Bl[(size_t)(2 * n + 0) * DIM + d] = (__bf16)(x0 - (float)h0);
        Bl[(size_t)(2 * n + 1) * DIM + d] = (__bf16)(x1 - (float)h1);
    }
}

#define CVT8(H, L, F0, F1) {                                   \
    float _v; __bf16 _h;                                       \
    _v = (F0).x; _h = (__bf16)_v; H[0] = _h; L[0] = (__bf16)(_v - (float)_h); \
    _v = (F0).y; _h = (__bf16)_v; H[1] = _h; L[1] = (__bf16)(_v - (float)_h); \
    _v = (F0).z; _h = (__bf16)_v; H[2] = _h; L[2] = (__bf16)(_v - (float)_h); \
    _v = (F0).w; _h = (__bf16)_v; H[3] = _h; L[3] = (__bf16)(_v - (float)_h); \
    _v = (F1).x; _h = (__bf16)_v; H[4] = _h; L[4] = (__bf16)(_v - (float)_h); \
    _v = (F1).y; _h = (__bf16)_v; H[5] = _h; L[5] = (__bf16)(_v - (float)_h); \
    _v = (F1).z; _h = (__bf16)_v; H[6] = _h; L[6] = (__bf16)(_v - (float)_h); \
    _v = (F1).w; _h = (__bf16)_v; H[7] = _h; L[7] = (__bf16)(_v - (float)_h); }

// 256 threads = 4 waves; wave owns 32 rows x all 128 cols. No LDS in K-loop.
__global__ __launch_bounds__(256) void gemm_fused(
    const float* __restrict__ A, const int* __restrict__ target,
    const __bf16* __restrict__ Bh, const __bf16* __restrict__ Bl,
    const float* __restrict__ bias,
    float* __restrict__ pred, float* __restrict__ outArg,
    float* __restrict__ partials)
{
    int tid  = threadIdx.x;
    int wave = tid >> 6;
    int lane = tid & 63;
    int q = lane >> 4;    // quad 0..3
    int c = lane & 15;    // col-within-tile / row-within-tile
    int rowBase = blockIdx.x * 128 + wave * 32;

    f32x4 acc[2][8] = {};

    const float*  a0p = A  + (size_t)(rowBase + c) * DIM + q * 8;
    const float*  a1p = a0p + (size_t)16 * DIM;
    const __bf16* bhp = Bh + (size_t)c * DIM + q * 8;
    const __bf16* blp = Bl + (size_t)c * DIM + q * 8;

#pragma unroll 2
    for (int s = 0; s < 16; ++s) {
        int k0 = s * 32;
        float4 x0 = *(const float4*)(a0p + k0);
        float4 x1 = *(const float4*)(a0p + k0 + 4);
        float4 y0 = *(const float4*)(a1p + k0);
        float4 y1 = *(const float4*)(a1p + k0 + 4);
        bf16x8 a0h, a0l, a1h, a1l;
        CVT8(a0h, a0l, x0, x1);
        CVT8(a1h, a1l, y0, y1);
#pragma unroll
        for (int nt = 0; nt < 8; ++nt) {
            bf16x8 bh = *(const bf16x8*)(bhp + (size_t)nt * 16 * DIM + k0);
            bf16x8 bl = *(const bf16x8*)(blp + (size_t)nt * 16 * DIM + k0);
            acc[0][nt] = __builtin_amdgcn_mfma_f32_16x16x32_bf16(a0h, bh, acc[0][nt], 0, 0, 0);
            acc[0][nt] = __builtin_amdgcn_mfma_f32_16x16x32_bf16(a0l, bh, acc[0][nt], 0, 0, 0);
            acc[0][nt] = __builtin_amdgcn_mfma_f32_16x16x32_bf16(a0h, bl, acc[0][nt], 0, 0, 0);
            acc[1][nt] = __builtin_amdgcn_mfma_f32_16x16x32_bf16(a1h, bh, acc[1][nt], 0, 0, 0);
            acc[1][nt] = __builtin_amdgcn_mfma_f32_16x16x32_bf16(a1l, bh, acc[1][nt], 0, 0, 0);
            acc[1][nt] = __builtin_amdgcn_mfma_f32_16x16x32_bf16(a1h, bl, acc[1][nt], 0, 0, 0);
        }
    }

    // ---- epilogue: bias, pred store, LSE over heads (axis=1), argmax, loss ----
    float bv[8];
#pragma unroll
    for (int nt = 0; nt < 8; ++nt) bv[nt] = bias[nt * 16 + c];

    float lp = 0.f;
#pragma unroll
    for (int mt = 0; mt < 2; ++mt) {
#pragma unroll
        for (int reg = 0; reg < 4; ++reg) {
            int row = rowBase + mt * 16 + q * 4 + reg;
            float p[8];
#pragma unroll
            for (int nt = 0; nt < 8; ++nt) p[nt] = acc[mt][nt][reg] + bv[nt];
#pragma unroll
            for (int nt = 0; nt < 8; ++nt)
                pred[(size_t)row * NCOL + nt * 16 + c] = p[nt];

            // max over own 8 cols (all same parity o=c&1), then butterfly over
            // lane bits 1..3 (stays in quad, preserves parity) -> 64-col max
            float M = p[0];
#pragma unroll
            for (int nt = 1; nt < 8; ++nt) M = fmaxf(M, p[nt]);
            M = fmaxf(M, __shfl_xor(M, 2, 64));
            M = fmaxf(M, __shfl_xor(M, 4, 64));
            M = fmaxf(M, __shfl_xor(M, 8, 64));
            float Mx = __shfl_xor(M, 1, 64);   // other parity's max

            float sE = 0.f;
#pragma unroll
            for (int nt = 0; nt < 8; ++nt) sE += expf(p[nt] - M);
            sE += __shfl_xor(sE, 2, 64);
            sE += __shfl_xor(sE, 4, 64);
            sE += __shfl_xor(sE, 8, 64);
            float sX = __shfl_xor(sE, 1, 64);

            float Lown = M + logf(sE);
            float Loth = Mx + logf(sX);
            float L0 = (c & 1) ? Loth : Lown;
            float L1 = (c & 1) ? Lown : Loth;

            float pn[8];
#pragma unroll
            for (int nt = 0; nt < 8; ++nt) pn[nt] = __shfl_xor(p[nt], 1, 64);

            if ((c & 1) == 0) {
                bool doA = (row >= FIX_ROWS);
                const int* trow = target + (size_t)row * NHEAD;
                float* arow = outArg + (size_t)row * NHEAD;
#pragma unroll
                for (int nt = 0; nt < 8; ++nt) {
                    int head = nt * 8 + (c >> 1);
                    int t = trow[head];
                    lp += t ? (L1 - pn[nt]) : (L0 - p[nt]);
                    if (doA) arow[head] = (pn[nt] > p[nt]) ? 1.f : 0.f;
                }
            }
        }
    }

    // deterministic loss partial per block
#pragma unroll
    for (int m = 32; m >= 1; m >>= 1) lp += __shfl_xor(lp, m, 64);
    __shared__ float wsum[4];
    if (lane == 0) wsum[wave] = lp;
    __syncthreads();
    if (tid == 0)
        partials[blockIdx.x] = (wsum[0] + wsum[1]) + (wsum[2] + wsum[3]);
}

// block 0: deterministic loss reduction + argmax rows 1056..1087
// blocks 1..66: argmax fixup rows 0..1055
__global__ __launch_bounds__(256) void fixup_kernel(
    const float* __restrict__ pred, const float* __restrict__ partials,
    float* __restrict__ outArg, float* __restrict__ lossOut)
{
    int tid = threadIdx.x;
    if (blockIdx.x == 0) {
        __shared__ double red[256];
        red[tid] = (double)partials[2 * tid] + (double)partials[2 * tid + 1];
        __syncthreads();
        for (int m = 128; m >= 1; m >>= 1) {
            if (tid < m) red[tid] += red[tid + m];
            __syncthreads();
        }
        if (tid == 0) lossOut[0] = (float)(red[0] / 131072.0);
        __syncthreads();
        int row = 1056 + (tid >> 3);
        int hb = (tid & 7) * 8;
        const float* pr = pred + (size_t)row * NCOL;
        float* ar = outArg + (size_t)row * NHEAD;
#pragma unroll
        for (int h = 0; h < 8; ++h) {
            float a = pr[2 * (hb + h)], b = pr[2 * (hb + h) + 1];
            ar[hb + h] = (b > a) ? 1.f : 0.f;
        }
    } else {
        int row = (blockIdx.x - 1) * 16 + (tid >> 4);
        int hb = (tid & 15) * 4;
        const float* pr = pred + (size_t)row * NCOL;
        float* ar = outArg + (size_t)row * NHEAD;
#pragma unroll
        for (int h = 0; h < 4; ++h) {
            float a = pr[2 * (hb + h)], b = pr[2 * (hb + h) + 1];
            ar[hb + h] = (b > a) ? 1.f : 0.f;
        }
    }
}

extern "C" void kernel_launch(void* const* d_in, const int* in_sizes, int n_in,
                              void* d_out, int out_size, void* d_ws, size_t ws_size,
                              hipStream_t stream) {
    const float* feature = (const float*)d_in[0];   // [65536,512]
    const int*   target  = (const int*)d_in[1];     // [65536,64]
    const float* W       = (const float*)d_in[2];   // [64,2,512]
    const float* bias    = (const float*)d_in[3];   // [64,2]
    const float* u       = (const float*)d_in[4];   // [64,2]

    float* out     = (float*)d_out;
    float* pred    = out;
    float* outArg  = out + ARG_BASE;
    float* lossOut = out + LOSS_IDX;
    __bf16* Bh     = (__bf16*)(out + BH_OFF);
    __bf16* Bl     = (__bf16*)(out + BL_OFF);
    float* partial = out + PART_OFF;

    spectral_kernel<<<NHEAD, 64, 0, stream>>>(W, u, Bh, Bl);
    gemm_fused<<<BROWS / 128, 256, 0, stream>>>(feature, target, Bh, Bl, bias,
                                                pred, outArg, partial);
    fixup_kernel<<<67, 256, 0, stream>>>(pred, partial, outArg, lossOut);
}

// Round 4
// 242.398 us; speedup vs baseline: 1.2638x; 1.1784x over previous
//
#include <hip/hip_runtime.h>
#include <math.h>

typedef __bf16 bf16x8 __attribute__((ext_vector_type(8)));
typedef float  f32x4  __attribute__((ext_vector_type(4)));

#define BROWS 65536
#define DIM   512
#define NHEAD 64
#define NCOL  128

#define PRED_SZ  ((size_t)BROWS * NCOL)            // 8388608 floats
#define ARG_BASE PRED_SZ
#define LOSS_IDX (PRED_SZ + (size_t)BROWS * NHEAD)
// Borrowed inside argmax region (rewritten by fixup):
//   rows    0..1023 : Bfrag, fragment-major hi/lo bf16, 131072 bf16 = 65536 floats
//   rows 1056..1087 : 1024 per-block loss partials
#define BF_OFF   ARG_BASE
#define PART_OFF (ARG_BASE + 1056 * (size_t)NHEAD)
#define FIX_ROWS 1088

// Bfrag element index for value BT[col][k] (col = head*2+o, k in [0,512)):
//   kc=k>>6, s=(k>>5)&1, q=(k>>3)&3, j=k&7, nt=col>>4, c=col&15, h in {0=hi,1=lo}
//   idx = kc*16384 + ((h*8+nt)*2+s)*512 + (q*16+c)*8 + j
// One frag-block = 512 bf16 = 1024 B = 64 lanes x 16 B (lane = q*16+c).

__global__ __launch_bounds__(64) void spectral_kernel(
    const float* __restrict__ W, const float* __restrict__ u,
    __bf16* __restrict__ Bfrag)
{
    int n = blockIdx.x;       // head
    int lane = threadIdx.x;   // 0..63; owns k = lane*8 .. lane*8+7

    const float* W0 = W + (size_t)n * 2 * DIM;
    const float* W1 = W0 + DIM;
    float u0 = u[2 * n], u1v = u[2 * n + 1];

    float w0[8], w1[8], vr[8];
    {
        float4 a0 = *(const float4*)(W0 + lane * 8);
        float4 a1 = *(const float4*)(W0 + lane * 8 + 4);
        float4 b0 = *(const float4*)(W1 + lane * 8);
        float4 b1 = *(const float4*)(W1 + lane * 8 + 4);
        w0[0]=a0.x; w0[1]=a0.y; w0[2]=a0.z; w0[3]=a0.w;
        w0[4]=a1.x; w0[5]=a1.y; w0[6]=a1.z; w0[7]=a1.w;
        w1[0]=b0.x; w1[1]=b0.y; w1[2]=b0.z; w1[3]=b0.w;
        w1[4]=b1.x; w1[5]=b1.y; w1[6]=b1.z; w1[7]=b1.w;
    }

    float ss = 0.f;
#pragma unroll
    for (int j = 0; j < 8; ++j) {
        vr[j] = fmaf(w0[j], u0, w1[j] * u1v);
        ss = fmaf(vr[j], vr[j], ss);
    }
#pragma unroll
    for (int m = 32; m >= 1; m >>= 1) ss += __shfl_xor(ss, m, 64);
    float inv_n = 1.f / fmaxf(sqrtf(ss), 1e-12f);

    float s0 = 0.f, s1 = 0.f;
#pragma unroll
    for (int j = 0; j < 8; ++j) {
        float v = vr[j] * inv_n;
        s0 = fmaf(w0[j], v, s0);
        s1 = fmaf(w1[j], v, s1);
    }
#pragma unroll
    for (int m = 32; m >= 1; m >>= 1) {
        s0 += __shfl_xor(s0, m, 64);
        s1 += __shfl_xor(s1, m, 64);
    }
    float nu = sqrtf(fmaf(s0, s0, s1 * s1));
    float inv_nu = 1.f / fmaxf(nu, 1e-12f);
    float sigma = fmaf(s0 * inv_nu, s0, (s1 * inv_nu) * s1);
    float inv_sigma = 1.f / sigma;

    int kc = lane >> 3;
    int s  = (lane >> 2) & 1;
    int q  = lane & 3;
#pragma unroll
    for (int o = 0; o < 2; ++o) {
        int col = 2 * n + o;
        int nt = col >> 4, cc = col & 15;
        bf16x8 hi, lo;
#pragma unroll
        for (int j = 0; j < 8; ++j) {
            float x = (o ? w1[j] : w0[j]) * inv_sigma;
            __bf16 h = (__bf16)x;
            hi[j] = h;
            lo[j] = (__bf16)(x - (float)h);
        }
        size_t base = (size_t)kc * 16384 + (size_t)(q * 16 + cc) * 8;
        *(bf16x8*)(Bfrag + base + (size_t)((0 * 8 + nt) * 2 + s) * 512) = hi;
        *(bf16x8*)(Bfrag + base + (size_t)((1 * 8 + nt) * 2 + s) * 512) = lo;
    }
}

#define CVT8(H, L, F0, F1) {                                   \
    float _v; __bf16 _h;                                       \
    _v = (F0).x; _h = (__bf16)_v; H[0] = _h; L[0] = (__bf16)(_v - (float)_h); \
    _v = (F0).y; _h = (__bf16)_v; H[1] = _h; L[1] = (__bf16)(_v - (float)_h); \
    _v = (F0).z; _h = (__bf16)_v; H[2] = _h; L[2] = (__bf16)(_v - (float)_h); \
    _v = (F0).w; _h = (__bf16)_v; H[3] = _h; L[3] = (__bf16)(_v - (float)_h); \
    _v = (F1).x; _h = (__bf16)_v; H[4] = _h; L[4] = (__bf16)(_v - (float)_h); \
    _v = (F1).y; _h = (__bf16)_v; H[5] = _h; L[5] = (__bf16)(_v - (float)_h); \
    _v = (F1).z; _h = (__bf16)_v; H[6] = _h; L[6] = (__bf16)(_v - (float)_h); \
    _v = (F1).w; _h = (__bf16)_v; H[7] = _h; L[7] = (__bf16)(_v - (float)_h); }

__device__ __forceinline__ void gld_lds16(const __bf16* g, __bf16* l) {
    __builtin_amdgcn_global_load_lds(
        (const __attribute__((address_space(1))) void*)g,
        (__attribute__((address_space(3))) void*)l, 16, 0, 0);
}

// 256 threads = 4 waves; wave owns 16 rows x all 128 cols; B via LDS chunks.
__global__ __launch_bounds__(256, 4) void gemm_fused(
    const float* __restrict__ A, const int* __restrict__ target,
    const __bf16* __restrict__ Bfrag, const float* __restrict__ bias,
    float* __restrict__ pred, float* __restrict__ outArg,
    float* __restrict__ partials)
{
    __shared__ __bf16 Bs[16384];   // 32 KB: one K-chunk (64 k) of B hi+lo, frag-major
    __shared__ float wsum[4];

    int tid  = threadIdx.x;
    int wave = tid >> 6;
    int lane = tid & 63;
    int q = lane >> 4;    // 0..3
    int c = lane & 15;    // 0..15
    int rowBase = blockIdx.x * 64 + wave * 16;

    f32x4 acc[8] = {};

    const float*  ap = A + (size_t)(rowBase + c) * DIM + q * 8;
    const __bf16* gB = Bfrag + (size_t)(wave * 8) * 512 + lane * 8;
    __bf16*       lB = Bs + (size_t)(wave * 8) * 512;

    float4 xa = *(const float4*)(ap + 0);
    float4 xb = *(const float4*)(ap + 4);
    float4 ya = *(const float4*)(ap + 32);
    float4 yb = *(const float4*)(ap + 36);

    for (int kc = 0; kc < 8; ++kc) {
        // stage B chunk kc (32 KB) via direct global->LDS DMA; 8 blocks per wave
#pragma unroll
        for (int t = 0; t < 8; ++t)
            gld_lds16(gB + (size_t)kc * 16384 + t * 512, lB + t * 512);

        // prefetch next chunk's A into registers (in flight across the barrier)
        int nb = (kc < 7) ? (kc + 1) * 64 : 0;
        float4 nxa = *(const float4*)(ap + nb);
        float4 nxb = *(const float4*)(ap + nb + 4);
        float4 nya = *(const float4*)(ap + nb + 32);
        float4 nyb = *(const float4*)(ap + nb + 36);

        __syncthreads();

        bf16x8 ah, al;
        CVT8(ah, al, xa, xb);   // s = 0
#pragma unroll
        for (int nt = 0; nt < 8; ++nt) {
            bf16x8 bh = *(const bf16x8*)(Bs + (size_t)((nt * 2 + 0) * 512) + lane * 8);
            bf16x8 bl = *(const bf16x8*)(Bs + (size_t)(((8 + nt) * 2 + 0) * 512) + lane * 8);
            acc[nt] = __builtin_amdgcn_mfma_f32_16x16x32_bf16(ah, bh, acc[nt], 0, 0, 0);
            acc[nt] = __builtin_amdgcn_mfma_f32_16x16x32_bf16(al, bh, acc[nt], 0, 0, 0);
            acc[nt] = __builtin_amdgcn_mfma_f32_16x16x32_bf16(ah, bl, acc[nt], 0, 0, 0);
        }
        CVT8(ah, al, ya, yb);   // s = 1
#pragma unroll
        for (int nt = 0; nt < 8; ++nt) {
            bf16x8 bh = *(const bf16x8*)(Bs + (size_t)((nt * 2 + 1) * 512) + lane * 8);
            bf16x8 bl = *(const bf16x8*)(Bs + (size_t)(((8 + nt) * 2 + 1) * 512) + lane * 8);
            acc[nt] = __builtin_amdgcn_mfma_f32_16x16x32_bf16(ah, bh, acc[nt], 0, 0, 0);
            acc[nt] = __builtin_amdgcn_mfma_f32_16x16x32_bf16(al, bh, acc[nt], 0, 0, 0);
            acc[nt] = __builtin_amdgcn_mfma_f32_16x16x32_bf16(ah, bl, acc[nt], 0, 0, 0);
        }
        __syncthreads();

        xa = nxa; xb = nxb; ya = nya; yb = nyb;
    }

    // ---- epilogue: bias, pred store, LSE over heads (axis=1), argmax, loss ----
    float bv[8];
#pragma unroll
    for (int nt = 0; nt < 8; ++nt) bv[nt] = bias[nt * 16 + c];

    float lp = 0.f;
    bool doA = (rowBase >= FIX_ROWS);
#pragma unroll
    for (int reg = 0; reg < 4; ++reg) {
        int row = rowBase + q * 4 + reg;
        float p[8];
#pragma unroll
        for (int nt = 0; nt < 8; ++nt) p[nt] = acc[nt][reg] + bv[nt];
#pragma unroll
        for (int nt = 0; nt < 8; ++nt)
            pred[(size_t)row * NCOL + nt * 16 + c] = p[nt];

        // max/sum over own 8 cols (same parity), butterfly lane bits 1..3
        float M = p[0];
#pragma unroll
        for (int nt = 1; nt < 8; ++nt) M = fmaxf(M, p[nt]);
        M = fmaxf(M, __shfl_xor(M, 2, 64));
        M = fmaxf(M, __shfl_xor(M, 4, 64));
        M = fmaxf(M, __shfl_xor(M, 8, 64));
        float Mx = __shfl_xor(M, 1, 64);

        float sE = 0.f;
#pragma unroll
        for (int nt = 0; nt < 8; ++nt) sE += expf(p[nt] - M);
        sE += __shfl_xor(sE, 2, 64);
        sE += __shfl_xor(sE, 4, 64);
        sE += __shfl_xor(sE, 8, 64);
        float sX = __shfl_xor(sE, 1, 64);

        float Lown = M + logf(sE);
        float Loth = Mx + logf(sX);
        float L0 = (c & 1) ? Loth : Lown;
        float L1 = (c & 1) ? Lown : Loth;

        float pn[8];
#pragma unroll
        for (int nt = 0; nt < 8; ++nt) pn[nt] = __shfl_xor(p[nt], 1, 64);

        if ((c & 1) == 0) {
            const int* trow = target + (size_t)row * NHEAD;
            float* arow = outArg + (size_t)row * NHEAD;
#pragma unroll
            for (int nt = 0; nt < 8; ++nt) {
                int head = nt * 8 + (c >> 1);
                int t = trow[head];
                lp += t ? (L1 - pn[nt]) : (L0 - p[nt]);
                if (doA) arow[head] = (pn[nt] > p[nt]) ? 1.f : 0.f;
            }
        }
    }

#pragma unroll
    for (int m = 32; m >= 1; m >>= 1) lp += __shfl_xor(lp, m, 64);
    if (lane == 0) wsum[wave] = lp;
    __syncthreads();
    if (tid == 0)
        partials[blockIdx.x] = (wsum[0] + wsum[1]) + (wsum[2] + wsum[3]);
}

// block 0: deterministic loss reduction + argmax rows 1056..1087
// blocks 1..66: argmax fixup rows 0..1055
__global__ __launch_bounds__(256) void fixup_kernel(
    const float* __restrict__ pred, const float* __restrict__ partials,
    float* __restrict__ outArg, float* __restrict__ lossOut)
{
    int tid = threadIdx.x;
    if (blockIdx.x == 0) {
        __shared__ double red[256];
        double s = 0.0;
#pragma unroll
        for (int i = 0; i < 4; ++i) s += (double)partials[tid * 4 + i];
        red[tid] = s;
        __syncthreads();
        for (int m = 128; m >= 1; m >>= 1) {
            if (tid < m) red[tid] += red[tid + m];
            __syncthreads();
        }
        if (tid == 0) lossOut[0] = (float)(red[0] / 131072.0);
        __syncthreads();
        int row = 1056 + (tid >> 3);
        int hb = (tid & 7) * 8;
        const float* pr = pred + (size_t)row * NCOL;
        float* ar = outArg + (size_t)row * NHEAD;
#pragma unroll
        for (int h = 0; h < 8; ++h) {
            float a = pr[2 * (hb + h)], b = pr[2 * (hb + h) + 1];
            ar[hb + h] = (b > a) ? 1.f : 0.f;
        }
    } else {
        int row = (blockIdx.x - 1) * 16 + (tid >> 4);
        int hb = (tid & 15) * 4;
        const float* pr = pred + (size_t)row * NCOL;
        float* ar = outArg + (size_t)row * NHEAD;
#pragma unroll
        for (int h = 0; h < 4; ++h) {
            float a = pr[2 * (hb + h)], b = pr[2 * (hb + h) + 1];
            ar[hb + h] = (b > a) ? 1.f : 0.f;
        }
    }
}

extern "C" void kernel_launch(void* const* d_in, const int* in_sizes, int n_in,
                              void* d_out, int out_size, void* d_ws, size_t ws_size,
                              hipStream_t stream) {
    const float* feature = (const float*)d_in[0];   // [65536,512]
    const int*   target  = (const int*)d_in[1];     // [65536,64]
    const float* W       = (const float*)d_in[2];   // [64,2,512]
    const float* bias    = (const float*)d_in[3];   // [64,2]
    const float* u       = (const float*)d_in[4];   // [64,2]

    float* out     = (float*)d_out;
    float* pred    = out;
    float* outArg  = out + ARG_BASE;
    float* lossOut = out + LOSS_IDX;
    __bf16* Bfrag  = (__bf16*)(out + BF_OFF);
    float* partial = out + PART_OFF;

    spectral_kernel<<<NHEAD, 64, 0, stream>>>(W, u, Bfrag);
    gemm_fused<<<BROWS / 64, 256, 0, stream>>>(feature, target, Bfrag, bias,
                                               pred, outArg, partial);
    fixup_kernel<<<67, 256, 0, stream>>>(pred, partial, outArg, lossOut);
}